// Round 8
// baseline (545.568 us; speedup 1.0000x reference)
//
#include <hip/hip_runtime.h>
#include <math.h>

#define D_FEAT 128
#define CAP 64            // bucket slots/row (512B stride, row-aligned lines)
#define OCAP 4096         // overflow list capacity
#define EPJ 1024          // edges per scatter job
#define GRID_BLOCKS 2048  // persistent blocks (8 blocks/CU at 256 thr)

static __device__ inline unsigned short f2bf(float f) {
    unsigned u = __float_as_uint(f);
    u += 0x7FFFu + ((u >> 16) & 1u);   // round-to-nearest-even
    return (unsigned short)(u >> 16);
}

// ctrl layout (ints): [0..7] per-partition chunk counters, [8] scale counter,
// [9] overflow count. Zeroed by memset together with cnt.

// ===================== fused persistent kernel ==============================
// Each block reads its REAL XCD via s_getreg(HW_REG_XCC_ID) and:
//   1) drains scatter jobs for partition p == its own XCD (rows with r&7==p),
//      so every bucket cache line is dirtied in exactly ONE XCD's L2;
//   2) takes logmap0-scale jobs (4 rows each) from a global counter;
//   3) rescues any partitions left undrained (exactly-once via the atomic
//      counters — correctness is independent of the XCD mapping, G16).
__global__ void __launch_bounds__(256)
fused_scatter_scale(const float* __restrict__ x,
                    unsigned short* __restrict__ xt,
                    const int* __restrict__ rows,
                    const int* __restrict__ cols,
                    const float* __restrict__ vals,
                    int* __restrict__ cnt,
                    int2* __restrict__ buckets,
                    int* __restrict__ ctrl,
                    int4* __restrict__ oedges,
                    int n_nodes, int n_edges,
                    int n_chunks, int n_scale_jobs) {
    __shared__ int s_job;
    unsigned xcc;
    asm volatile("s_getreg_b32 %0, hwreg(HW_REG_XCC_ID, 0, 32)" : "=s"(xcc));
    const int myp = (int)(xcc & 7u);

    // ---- phase 1+3: scatter own partition first, then rescue others ----
    for (int d = 0; d < 8; ++d) {
        if (d == 1) {
            // ---- phase 2 (between own-drain and rescue): scale jobs ----
            while (true) {
                if (threadIdx.x == 0) s_job = atomicAdd(&ctrl[8], 1);
                __syncthreads();
                int s = s_job;
                __syncthreads();
                if (s >= n_scale_jobs) break;
                const int lane = threadIdx.x & 63;
                const int wave = threadIdx.x >> 6;
                const int row = s * 4 + wave;
                if (row < n_nodes) {
                    const float2* xr = (const float2*)(x + (size_t)row * D_FEAT);
                    float2 v = xr[lane];
                    float ss = v.x * v.x + v.y * v.y;
                    #pragma unroll
                    for (int off = 32; off > 0; off >>= 1)
                        ss += __shfl_xor(ss, off, 64);
                    float norm = sqrtf(ss);
                    float nc = fmaxf(norm, 1e-15f);
                    float u = fminf(nc, 1.0f - 1e-15f);
                    float at = 0.5f * (log1pf(u) - log1pf(-u));
                    float sc = at / nc;
                    ushort2 o;
                    o.x = f2bf(v.x * sc);
                    o.y = f2bf(v.y * sc);
                    ((ushort2*)(xt + (size_t)row * D_FEAT))[lane] = o;
                }
            }
        }
        const int q = (myp + d) & 7;
        while (true) {
            if (threadIdx.x == 0) s_job = atomicAdd(&ctrl[q], 1);
            __syncthreads();
            int c = s_job;
            __syncthreads();
            if (c >= n_chunks) break;
            int base = c * EPJ + threadIdx.x;
            #pragma unroll
            for (int k = 0; k < 4; ++k) {
                int e = base + k * 256;
                if (e < n_edges) {
                    int r = rows[e];
                    if ((r & 7) == q) {
                        int slot = atomicAdd(&cnt[r], 1);
                        int2 p;
                        p.x = cols[e];
                        p.y = __float_as_int(vals[e]);
                        if (slot < CAP) {
                            buckets[(size_t)r * CAP + slot] = p;
                        } else {           // rare overflow
                            int o = atomicAdd(&ctrl[9], 1);
                            if (o < OCAP) {
                                int4 qq; qq.x = r; qq.y = p.x; qq.z = p.y; qq.w = 0;
                                oedges[o] = qq;
                            }
                        }
                    }
                }
            }
        }
    }
}

// ===================== gather: 16B loads, 4 edges per wave-round ============
// lane = g*16 + t (g in [0,4), t in [0,16)). Group g handles edge j+g; lane
// loads uint4 = 8 bf16 features at offset t*16B. One VMEM instruction covers
// 4 edges (1KB). Epilogue: shfl_xor(16,32) reduction across groups, 16 lanes
// store 32B each.
__global__ void __launch_bounds__(256)
gather_bucket_kernel(const unsigned short* __restrict__ xt,
                     const int* __restrict__ cnt,
                     const int2* __restrict__ buckets,
                     float* __restrict__ out, int n_nodes) {
    const int lane = threadIdx.x & 63;
    const int wave = threadIdx.x >> 6;
    const int row = blockIdx.x * 4 + wave;
    if (row >= n_nodes) return;

    int deg = cnt[row];
    deg = deg < CAP ? deg : CAP;

    int2 myp = {0, 0};
    if (lane < deg) myp = buckets[(size_t)row * CAP + lane];  // coalesced
    int pc = myp.x;
    float pw = __int_as_float(myp.y);

    const int g = lane >> 4;
    const int t = lane & 15;

    float a0 = 0, a1 = 0, a2 = 0, a3 = 0, a4 = 0, a5 = 0, a6 = 0, a7 = 0;

    for (int j = 0; j < deg; j += 8) {
        int i0 = j + g, i1 = j + 4 + g;
        int i0c = i0 < deg ? i0 : 0;
        int i1c = i1 < deg ? i1 : 0;
        int c0 = __shfl(pc, i0c, 64);
        int c1 = __shfl(pc, i1c, 64);
        float w0 = __shfl(pw, i0c, 64);
        float w1 = __shfl(pw, i1c, 64);
        if (i0 >= deg) w0 = 0.0f;
        if (i1 >= deg) w1 = 0.0f;
        uint4 u0 = ((const uint4*)(xt + ((size_t)c0 << 7)))[t];
        uint4 u1 = ((const uint4*)(xt + ((size_t)c1 << 7)))[t];
        a0 = fmaf(w0, __uint_as_float(u0.x << 16), a0);
        a1 = fmaf(w0, __uint_as_float(u0.x & 0xFFFF0000u), a1);
        a2 = fmaf(w0, __uint_as_float(u0.y << 16), a2);
        a3 = fmaf(w0, __uint_as_float(u0.y & 0xFFFF0000u), a3);
        a4 = fmaf(w0, __uint_as_float(u0.z << 16), a4);
        a5 = fmaf(w0, __uint_as_float(u0.z & 0xFFFF0000u), a5);
        a6 = fmaf(w0, __uint_as_float(u0.w << 16), a6);
        a7 = fmaf(w0, __uint_as_float(u0.w & 0xFFFF0000u), a7);
        a0 = fmaf(w1, __uint_as_float(u1.x << 16), a0);
        a1 = fmaf(w1, __uint_as_float(u1.x & 0xFFFF0000u), a1);
        a2 = fmaf(w1, __uint_as_float(u1.y << 16), a2);
        a3 = fmaf(w1, __uint_as_float(u1.y & 0xFFFF0000u), a3);
        a4 = fmaf(w1, __uint_as_float(u1.z << 16), a4);
        a5 = fmaf(w1, __uint_as_float(u1.z & 0xFFFF0000u), a5);
        a6 = fmaf(w1, __uint_as_float(u1.w << 16), a6);
        a7 = fmaf(w1, __uint_as_float(u1.w & 0xFFFF0000u), a7);
    }

    // reduce across the 4 groups
    a0 += __shfl_xor(a0, 16, 64); a0 += __shfl_xor(a0, 32, 64);
    a1 += __shfl_xor(a1, 16, 64); a1 += __shfl_xor(a1, 32, 64);
    a2 += __shfl_xor(a2, 16, 64); a2 += __shfl_xor(a2, 32, 64);
    a3 += __shfl_xor(a3, 16, 64); a3 += __shfl_xor(a3, 32, 64);
    a4 += __shfl_xor(a4, 16, 64); a4 += __shfl_xor(a4, 32, 64);
    a5 += __shfl_xor(a5, 16, 64); a5 += __shfl_xor(a5, 32, 64);
    a6 += __shfl_xor(a6, 16, 64); a6 += __shfl_xor(a6, 32, 64);
    a7 += __shfl_xor(a7, 16, 64); a7 += __shfl_xor(a7, 32, 64);

    if (g == 0) {
        float4* op = (float4*)(out + ((size_t)row << 7) + t * 8);
        float4 o0; o0.x = a0; o0.y = a1; o0.z = a2; o0.w = a3;
        float4 o1; o1.x = a4; o1.y = a5; o1.z = a6; o1.w = a7;
        op[0] = o0;
        op[1] = o1;
    }
}

// Cleanup: overflow edges (normally zero) — atomic add into out after gather.
__global__ void cleanup_kernel(const unsigned short* __restrict__ xt,
                               const int* __restrict__ ctrl,
                               const int4* __restrict__ oedges,
                               float* __restrict__ out) {
    int tt = blockIdx.x * blockDim.x + threadIdx.x;
    int e = tt >> 5, sub = tt & 31;
    int n = ctrl[9];
    n = n < OCAP ? n : OCAP;
    if (e >= n) return;
    int4 q = oedges[e];
    float w = __int_as_float(q.z);
    const unsigned* xr = (const unsigned*)(xt + ((size_t)q.y << 7));
    unsigned u0 = xr[sub * 2], u1 = xr[sub * 2 + 1];
    float* o = out + ((size_t)q.x << 7) + sub * 4;
    atomicAdd(o + 0, w * __uint_as_float(u0 << 16));
    atomicAdd(o + 1, w * __uint_as_float(u0 & 0xFFFF0000u));
    atomicAdd(o + 2, w * __uint_as_float(u1 << 16));
    atomicAdd(o + 3, w * __uint_as_float(u1 & 0xFFFF0000u));
}

// ===================== fallback (tiny ws; never expected) ===================
__global__ void fallback_kernel(const float* __restrict__ x,
                                const int* __restrict__ rows,
                                const int* __restrict__ cols,
                                const float* __restrict__ vals,
                                float* __restrict__ out, int n_edges) {
    int gid = blockIdx.x * blockDim.x + threadIdx.x;
    int e = gid >> 5, t = gid & 31;
    if (e >= n_edges) return;
    int c = cols[e];
    const float* xr = x + (size_t)c * D_FEAT;
    float ss = 0.0f;
    for (int i = 0; i < D_FEAT; ++i) ss += xr[i] * xr[i];
    float nc = fmaxf(sqrtf(ss), 1e-15f);
    float u = fminf(nc, 1.0f - 1e-15f);
    float w = vals[e] * (0.5f * (log1pf(u) - log1pf(-u))) / nc;
    const float4* xc = (const float4*)xr;
    float4 xv = xc[t];
    float* o = out + (size_t)rows[e] * D_FEAT + t * 4;
    atomicAdd(o + 0, w * xv.x);
    atomicAdd(o + 1, w * xv.y);
    atomicAdd(o + 2, w * xv.z);
    atomicAdd(o + 3, w * xv.w);
}

// ============================================================================

extern "C" void kernel_launch(void* const* d_in, const int* in_sizes, int n_in,
                              void* d_out, int out_size, void* d_ws, size_t ws_size,
                              hipStream_t stream) {
    const float* x    = (const float*)d_in[0];
    const int*   rows = (const int*)d_in[1];
    const int*   cols = (const int*)d_in[2];
    const float* vals = (const float*)d_in[3];
    float* out = (float*)d_out;

    const int n_nodes = in_sizes[0] / D_FEAT;  // 50000
    const int n_edges = in_sizes[1];           // 800000

    char* wsb = (char*)d_ws;
    const int n_chunks = (n_edges + EPJ - 1) / EPJ;        // 782
    const int n_scale_jobs = (n_nodes + 3) / 4;            // 12500

    size_t xt_bytes    = (size_t)n_nodes * D_FEAT * 2;            // 12.8 MB
    size_t cnt_off     = xt_bytes;
    size_t ctrl_off    = cnt_off + (size_t)n_nodes * 4;           // 16 ints
    size_t oedges_off  = (ctrl_off + 64 + 255) & ~(size_t)255;
    size_t buckets_off = (oedges_off + (size_t)OCAP * 16 + 511) & ~(size_t)511;
    size_t need        = buckets_off + (size_t)n_nodes * CAP * 8; // ~38.7 MB

    if (ws_size >= need) {
        unsigned short* xt = (unsigned short*)wsb;
        int*  cnt     = (int*)(wsb + cnt_off);
        int*  ctrl    = (int*)(wsb + ctrl_off);
        int4* oedges  = (int4*)(wsb + oedges_off);
        int2* buckets = (int2*)(wsb + buckets_off);

        // zero cnt + ctrl in one memset
        hipMemsetAsync(cnt, 0, (ctrl_off + 64) - cnt_off, stream);
        fused_scatter_scale<<<GRID_BLOCKS, 256, 0, stream>>>(
            x, xt, rows, cols, vals, cnt, buckets, ctrl, oedges,
            n_nodes, n_edges, n_chunks, n_scale_jobs);
        gather_bucket_kernel<<<(n_nodes + 3) / 4, 256, 0, stream>>>(
            xt, cnt, buckets, out, n_nodes);
        cleanup_kernel<<<(OCAP * 32) / 256, 256, 0, stream>>>(xt, ctrl, oedges, out);
    } else {
        hipMemsetAsync(out, 0, (size_t)out_size * sizeof(float), stream);
        long long total = (long long)n_edges * 32;
        fallback_kernel<<<(int)((total + 255) / 256), 256, 0, stream>>>(
            x, rows, cols, vals, out, n_edges);
    }
}

// Round 9
// 183.648 us; speedup vs baseline: 2.9707x; 2.9707x over previous
//
#include <hip/hip_runtime.h>
#include <math.h>

#define D_FEAT 128
#define CAP 32            // bucket slots/row (256B stride); Poisson(16) tail -> cleanup
#define OCAP 4096         // overflow list capacity

typedef float  v2f __attribute__((ext_vector_type(2)));
typedef int    v2i __attribute__((ext_vector_type(2)));
typedef float  v4f __attribute__((ext_vector_type(4)));
typedef unsigned v4u __attribute__((ext_vector_type(4)));

static __device__ inline unsigned short f2bf(float f) {
    unsigned u = __float_as_uint(f);
    u += 0x7FFFu + ((u >> 16) & 1u);   // round-to-nearest-even
    return (unsigned short)(u >> 16);
}

// ===================== fused scatter + scale ================================
// Scatter role (blocks [0, nsb), dispatched first): single pass over edges,
// NT loads for the edge stream (no L2 pollution), NT stores for bucket
// entries (stream past L2 with byte enables -> no partial-line eviction
// churn; R8 falsified the cross-XCD theory, R6/R8 WRITE ~57MB is single-L2
// eviction epochs). Scale role: per-row logmap0 + bf16 row, NT in/out.
__global__ void __launch_bounds__(256)
scatter_scale_kernel(const float* __restrict__ x,
                     unsigned short* __restrict__ xt,
                     const int* __restrict__ rows,
                     const int* __restrict__ cols,
                     const float* __restrict__ vals,
                     int* __restrict__ cnt,
                     int* __restrict__ buckets,   // int2 entries, flat
                     int* __restrict__ ocount,
                     int4* __restrict__ oedges,
                     int n_nodes, int n_edges,
                     int n_scatter_blocks) {
    if ((int)blockIdx.x < n_scatter_blocks) {
        int base = blockIdx.x * 1024 + threadIdx.x;
        #pragma unroll
        for (int k = 0; k < 4; ++k) {
            int e = base + k * 256;
            if (e < n_edges) {
                int   r = __builtin_nontemporal_load(rows + e);
                int   c = __builtin_nontemporal_load(cols + e);
                float v = __builtin_nontemporal_load(vals + e);
                int slot = atomicAdd(&cnt[r], 1);
                if (slot < CAP) {
                    v2i p;
                    p.x = c;
                    p.y = __float_as_int(v);
                    __builtin_nontemporal_store(
                        p, (v2i*)(buckets + 2 * ((size_t)r * CAP + slot)));
                } else {  // rare (Poisson tail): exact via cleanup
                    int o = atomicAdd(ocount, 1);
                    if (o < OCAP) {
                        int4 q; q.x = r; q.y = c; q.z = __float_as_int(v); q.w = 0;
                        oedges[o] = q;
                    }
                }
            }
        }
    } else {
        const int lane = threadIdx.x & 63;
        const int wave = threadIdx.x >> 6;
        const int row = ((int)blockIdx.x - n_scatter_blocks) * 4 + wave;
        if (row >= n_nodes) return;

        v2f v = __builtin_nontemporal_load(
            (const v2f*)(x + (size_t)row * D_FEAT) + lane);
        float ss = v.x * v.x + v.y * v.y;
        #pragma unroll
        for (int off = 32; off > 0; off >>= 1)
            ss += __shfl_xor(ss, off, 64);

        float norm = sqrtf(ss);
        float nc = fmaxf(norm, 1e-15f);
        float u = fminf(nc, 1.0f - 1e-15f);
        float at = 0.5f * (log1pf(u) - log1pf(-u));
        float s = at / nc;

        unsigned packed = (unsigned)f2bf(v.x * s) |
                          ((unsigned)f2bf(v.y * s) << 16);
        __builtin_nontemporal_store(
            packed, (unsigned*)(xt + (size_t)row * D_FEAT) + lane);
    }
}

// ===================== gather: 16B loads, 4 edges per wave-round ============
// lane = g*16 + t. Group g handles edge j+g; lane loads 8 bf16 features
// (16B) at offset t*16B — one VMEM instr covers 4 edges. Cross-group
// shfl_xor(16,32) reduce; group 0 stores 2x float4 (NT).
__global__ void __launch_bounds__(256)
gather_bucket_kernel(const unsigned short* __restrict__ xt,
                     const int* __restrict__ cnt,
                     const int* __restrict__ buckets,
                     float* __restrict__ out, int n_nodes) {
    const int lane = threadIdx.x & 63;
    const int wave = threadIdx.x >> 6;
    const int row = blockIdx.x * 4 + wave;
    if (row >= n_nodes) return;

    int deg = cnt[row];
    deg = deg < CAP ? deg : CAP;

    v2i myp = {0, 0};
    if (lane < deg)
        myp = ((const v2i*)(buckets + 2 * (size_t)row * CAP))[lane];
    int pc = myp.x;
    float pw = __int_as_float(myp.y);

    const int g = lane >> 4;
    const int t = lane & 15;

    float a0 = 0, a1 = 0, a2 = 0, a3 = 0, a4 = 0, a5 = 0, a6 = 0, a7 = 0;

    for (int j = 0; j < deg; j += 8) {
        int i0 = j + g, i1 = j + 4 + g;
        int i0c = i0 < deg ? i0 : 0;
        int i1c = i1 < deg ? i1 : 0;
        int c0 = __shfl(pc, i0c, 64);
        int c1 = __shfl(pc, i1c, 64);
        float w0 = __shfl(pw, i0c, 64);
        float w1 = __shfl(pw, i1c, 64);
        if (i0 >= deg) w0 = 0.0f;
        if (i1 >= deg) w1 = 0.0f;
        v4u u0 = ((const v4u*)(xt + ((size_t)c0 << 7)))[t];
        v4u u1 = ((const v4u*)(xt + ((size_t)c1 << 7)))[t];
        a0 = fmaf(w0, __uint_as_float(u0.x << 16), a0);
        a1 = fmaf(w0, __uint_as_float(u0.x & 0xFFFF0000u), a1);
        a2 = fmaf(w0, __uint_as_float(u0.y << 16), a2);
        a3 = fmaf(w0, __uint_as_float(u0.y & 0xFFFF0000u), a3);
        a4 = fmaf(w0, __uint_as_float(u0.z << 16), a4);
        a5 = fmaf(w0, __uint_as_float(u0.z & 0xFFFF0000u), a5);
        a6 = fmaf(w0, __uint_as_float(u0.w << 16), a6);
        a7 = fmaf(w0, __uint_as_float(u0.w & 0xFFFF0000u), a7);
        a0 = fmaf(w1, __uint_as_float(u1.x << 16), a0);
        a1 = fmaf(w1, __uint_as_float(u1.x & 0xFFFF0000u), a1);
        a2 = fmaf(w1, __uint_as_float(u1.y << 16), a2);
        a3 = fmaf(w1, __uint_as_float(u1.y & 0xFFFF0000u), a3);
        a4 = fmaf(w1, __uint_as_float(u1.z << 16), a4);
        a5 = fmaf(w1, __uint_as_float(u1.z & 0xFFFF0000u), a5);
        a6 = fmaf(w1, __uint_as_float(u1.w << 16), a6);
        a7 = fmaf(w1, __uint_as_float(u1.w & 0xFFFF0000u), a7);
    }

    a0 += __shfl_xor(a0, 16, 64); a0 += __shfl_xor(a0, 32, 64);
    a1 += __shfl_xor(a1, 16, 64); a1 += __shfl_xor(a1, 32, 64);
    a2 += __shfl_xor(a2, 16, 64); a2 += __shfl_xor(a2, 32, 64);
    a3 += __shfl_xor(a3, 16, 64); a3 += __shfl_xor(a3, 32, 64);
    a4 += __shfl_xor(a4, 16, 64); a4 += __shfl_xor(a4, 32, 64);
    a5 += __shfl_xor(a5, 16, 64); a5 += __shfl_xor(a5, 32, 64);
    a6 += __shfl_xor(a6, 16, 64); a6 += __shfl_xor(a6, 32, 64);
    a7 += __shfl_xor(a7, 16, 64); a7 += __shfl_xor(a7, 32, 64);

    if (g == 0) {
        v4f* op = (v4f*)(out + ((size_t)row << 7) + t * 8);
        v4f o0; o0.x = a0; o0.y = a1; o0.z = a2; o0.w = a3;
        v4f o1; o1.x = a4; o1.y = a5; o1.z = a6; o1.w = a7;
        __builtin_nontemporal_store(o0, op);
        __builtin_nontemporal_store(o1, op + 1);
    }
}

// Cleanup: overflow edges (tens at most) — atomic add into out after gather.
__global__ void cleanup_kernel(const unsigned short* __restrict__ xt,
                               const int* __restrict__ ocount,
                               const int4* __restrict__ oedges,
                               float* __restrict__ out) {
    int tt = blockIdx.x * blockDim.x + threadIdx.x;
    int e = tt >> 5, sub = tt & 31;
    int n = *ocount;
    n = n < OCAP ? n : OCAP;
    if (e >= n) return;
    int4 q = oedges[e];
    float w = __int_as_float(q.z);
    const unsigned* xr = (const unsigned*)(xt + ((size_t)q.y << 7));
    unsigned u0 = xr[sub * 2], u1 = xr[sub * 2 + 1];
    float* o = out + ((size_t)q.x << 7) + sub * 4;
    atomicAdd(o + 0, w * __uint_as_float(u0 << 16));
    atomicAdd(o + 1, w * __uint_as_float(u0 & 0xFFFF0000u));
    atomicAdd(o + 2, w * __uint_as_float(u1 << 16));
    atomicAdd(o + 3, w * __uint_as_float(u1 & 0xFFFF0000u));
}

// ===================== fallback (tiny ws; never expected) ===================
__global__ void fallback_kernel(const float* __restrict__ x,
                                const int* __restrict__ rows,
                                const int* __restrict__ cols,
                                const float* __restrict__ vals,
                                float* __restrict__ out, int n_edges) {
    int gid = blockIdx.x * blockDim.x + threadIdx.x;
    int e = gid >> 5, t = gid & 31;
    if (e >= n_edges) return;
    int c = cols[e];
    const float* xr = x + (size_t)c * D_FEAT;
    float ss = 0.0f;
    for (int i = 0; i < D_FEAT; ++i) ss += xr[i] * xr[i];
    float nc = fmaxf(sqrtf(ss), 1e-15f);
    float u = fminf(nc, 1.0f - 1e-15f);
    float w = vals[e] * (0.5f * (log1pf(u) - log1pf(-u))) / nc;
    const float4* xc = (const float4*)xr;
    float4 xv = xc[t];
    float* o = out + (size_t)rows[e] * D_FEAT + t * 4;
    atomicAdd(o + 0, w * xv.x);
    atomicAdd(o + 1, w * xv.y);
    atomicAdd(o + 2, w * xv.z);
    atomicAdd(o + 3, w * xv.w);
}

// ============================================================================

extern "C" void kernel_launch(void* const* d_in, const int* in_sizes, int n_in,
                              void* d_out, int out_size, void* d_ws, size_t ws_size,
                              hipStream_t stream) {
    const float* x    = (const float*)d_in[0];
    const int*   rows = (const int*)d_in[1];
    const int*   cols = (const int*)d_in[2];
    const float* vals = (const float*)d_in[3];
    float* out = (float*)d_out;

    const int n_nodes = in_sizes[0] / D_FEAT;  // 50000
    const int n_edges = in_sizes[1];           // 800000

    char* wsb = (char*)d_ws;
    const int n_scatter_blocks = (n_edges + 1023) / 1024;  // 782
    const int n_scale_blocks   = (n_nodes + 3) / 4;        // 12500

    size_t xt_bytes    = (size_t)n_nodes * D_FEAT * 2;            // 12.8 MB
    size_t cnt_off     = xt_bytes;
    size_t ocount_off  = cnt_off + (size_t)n_nodes * 4;
    size_t oedges_off  = (ocount_off + 4 + 255) & ~(size_t)255;
    size_t buckets_off = (oedges_off + (size_t)OCAP * 16 + 511) & ~(size_t)511;
    size_t need        = buckets_off + (size_t)n_nodes * CAP * 8; // ~26 MB

    if (ws_size >= need) {
        unsigned short* xt = (unsigned short*)wsb;
        int*  cnt     = (int*)(wsb + cnt_off);
        int*  ocount  = (int*)(wsb + ocount_off);
        int4* oedges  = (int4*)(wsb + oedges_off);
        int*  buckets = (int*)(wsb + buckets_off);

        hipMemsetAsync(cnt, 0, ocount_off + 4 - cnt_off, stream);
        scatter_scale_kernel<<<n_scatter_blocks + n_scale_blocks, 256, 0, stream>>>(
            x, xt, rows, cols, vals, cnt, buckets, ocount, oedges,
            n_nodes, n_edges, n_scatter_blocks);
        gather_bucket_kernel<<<(n_nodes + 3) / 4, 256, 0, stream>>>(
            xt, cnt, buckets, out, n_nodes);
        cleanup_kernel<<<(OCAP * 32) / 256, 256, 0, stream>>>(xt, ocount, oedges, out);
    } else {
        hipMemsetAsync(out, 0, (size_t)out_size * sizeof(float), stream);
        long long total = (long long)n_edges * 32;
        fallback_kernel<<<(int)((total + 255) / 256), 256, 0, stream>>>(
            x, rows, cols, vals, out, n_edges);
    }
}

// Round 10
// 169.738 us; speedup vs baseline: 3.2142x; 1.0820x over previous
//
#include <hip/hip_runtime.h>
#include <math.h>

#define D_FEAT 128
#define CAP 32            // bucket slots/row (256B stride); Poisson(16) tail -> cleanup
#define OCAP 4096         // overflow list capacity

typedef float  v2f __attribute__((ext_vector_type(2)));
typedef int    v2i __attribute__((ext_vector_type(2)));
typedef float  v4f __attribute__((ext_vector_type(4)));
typedef unsigned v4u __attribute__((ext_vector_type(4)));

static __device__ inline unsigned short f2bf(float f) {
    unsigned u = __float_as_uint(f);
    u += 0x7FFFu + ((u >> 16) & 1u);   // round-to-nearest-even
    return (unsigned short)(u >> 16);
}

// ===================== fused scatter + scale ================================
// Scatter role (blocks [0, nsb), dispatched first): 2048 edges/block, 8 per
// thread, phase-batched for 8-deep atomic MLP. Edge stream + x are NT loads
// (keep L2 clean); bucket stores are NORMAL cached stores so L2 write-
// combines a row's ~16 edge entries into ~2 full sectors, written back ONCE
// at kernel-end flush (R9 falsified NT stores: write-through = 64B/edge).
// xt is NT-stored (contiguous fully-dirty lines, nothing to combine).
__global__ void __launch_bounds__(256)
scatter_scale_kernel(const float* __restrict__ x,
                     unsigned short* __restrict__ xt,
                     const int* __restrict__ rows,
                     const int* __restrict__ cols,
                     const float* __restrict__ vals,
                     int* __restrict__ cnt,
                     int* __restrict__ buckets,   // int2 entries, flat
                     int* __restrict__ ocount,
                     int4* __restrict__ oedges,
                     int n_nodes, int n_edges,
                     int n_scatter_blocks) {
    if ((int)blockIdx.x < n_scatter_blocks) {
        const int base = blockIdx.x * 2048 + threadIdx.x;
        int   r[8]; int cc[8]; float vv[8]; bool ok[8]; int slot[8];
        #pragma unroll
        for (int k = 0; k < 8; ++k) {
            int e = base + k * 256;
            ok[k] = e < n_edges;
            r[k]  = ok[k] ? __builtin_nontemporal_load(rows + e) : 0;
            cc[k] = ok[k] ? __builtin_nontemporal_load(cols + e) : 0;
            vv[k] = ok[k] ? __builtin_nontemporal_load(vals + e) : 0.0f;
        }
        #pragma unroll
        for (int k = 0; k < 8; ++k)
            slot[k] = ok[k] ? atomicAdd(&cnt[r[k]], 1) : 0;
        #pragma unroll
        for (int k = 0; k < 8; ++k) {
            if (ok[k]) {
                v2i p;
                p.x = cc[k];
                p.y = __float_as_int(vv[k]);
                if (slot[k] < CAP) {
                    *((v2i*)(buckets + 2 * ((size_t)r[k] * CAP + slot[k]))) = p;
                } else {  // rare (Poisson tail): exact via cleanup
                    int o = atomicAdd(ocount, 1);
                    if (o < OCAP) {
                        int4 q; q.x = r[k]; q.y = p.x; q.z = p.y; q.w = 0;
                        oedges[o] = q;
                    }
                }
            }
        }
    } else {
        const int lane = threadIdx.x & 63;
        const int wave = threadIdx.x >> 6;
        const int row = ((int)blockIdx.x - n_scatter_blocks) * 4 + wave;
        if (row >= n_nodes) return;

        v2f v = __builtin_nontemporal_load(
            (const v2f*)(x + (size_t)row * D_FEAT) + lane);
        float ss = v.x * v.x + v.y * v.y;
        #pragma unroll
        for (int off = 32; off > 0; off >>= 1)
            ss += __shfl_xor(ss, off, 64);

        float norm = sqrtf(ss);
        float nc = fmaxf(norm, 1e-15f);
        float u = fminf(nc, 1.0f - 1e-15f);
        float at = 0.5f * (log1pf(u) - log1pf(-u));
        float s = at / nc;

        unsigned packed = (unsigned)f2bf(v.x * s) |
                          ((unsigned)f2bf(v.y * s) << 16);
        __builtin_nontemporal_store(
            packed, (unsigned*)(xt + (size_t)row * D_FEAT) + lane);
    }
}

// ===================== gather: 16B loads, 4 edges per wave-round ============
__global__ void __launch_bounds__(256)
gather_bucket_kernel(const unsigned short* __restrict__ xt,
                     const int* __restrict__ cnt,
                     const int* __restrict__ buckets,
                     float* __restrict__ out, int n_nodes) {
    const int lane = threadIdx.x & 63;
    const int wave = threadIdx.x >> 6;
    const int row = blockIdx.x * 4 + wave;
    if (row >= n_nodes) return;

    int deg = cnt[row];
    deg = deg < CAP ? deg : CAP;

    v2i myp = {0, 0};
    if (lane < deg)
        myp = ((const v2i*)(buckets + 2 * (size_t)row * CAP))[lane];
    int pc = myp.x;
    float pw = __int_as_float(myp.y);

    const int g = lane >> 4;
    const int t = lane & 15;

    float a0 = 0, a1 = 0, a2 = 0, a3 = 0, a4 = 0, a5 = 0, a6 = 0, a7 = 0;

    for (int j = 0; j < deg; j += 8) {
        int i0 = j + g, i1 = j + 4 + g;
        int i0c = i0 < deg ? i0 : 0;
        int i1c = i1 < deg ? i1 : 0;
        int c0 = __shfl(pc, i0c, 64);
        int c1 = __shfl(pc, i1c, 64);
        float w0 = __shfl(pw, i0c, 64);
        float w1 = __shfl(pw, i1c, 64);
        if (i0 >= deg) w0 = 0.0f;
        if (i1 >= deg) w1 = 0.0f;
        v4u u0 = ((const v4u*)(xt + ((size_t)c0 << 7)))[t];
        v4u u1 = ((const v4u*)(xt + ((size_t)c1 << 7)))[t];
        a0 = fmaf(w0, __uint_as_float(u0.x << 16), a0);
        a1 = fmaf(w0, __uint_as_float(u0.x & 0xFFFF0000u), a1);
        a2 = fmaf(w0, __uint_as_float(u0.y << 16), a2);
        a3 = fmaf(w0, __uint_as_float(u0.y & 0xFFFF0000u), a3);
        a4 = fmaf(w0, __uint_as_float(u0.z << 16), a4);
        a5 = fmaf(w0, __uint_as_float(u0.z & 0xFFFF0000u), a5);
        a6 = fmaf(w0, __uint_as_float(u0.w << 16), a6);
        a7 = fmaf(w0, __uint_as_float(u0.w & 0xFFFF0000u), a7);
        a0 = fmaf(w1, __uint_as_float(u1.x << 16), a0);
        a1 = fmaf(w1, __uint_as_float(u1.x & 0xFFFF0000u), a1);
        a2 = fmaf(w1, __uint_as_float(u1.y << 16), a2);
        a3 = fmaf(w1, __uint_as_float(u1.y & 0xFFFF0000u), a3);
        a4 = fmaf(w1, __uint_as_float(u1.z << 16), a4);
        a5 = fmaf(w1, __uint_as_float(u1.z & 0xFFFF0000u), a5);
        a6 = fmaf(w1, __uint_as_float(u1.w << 16), a6);
        a7 = fmaf(w1, __uint_as_float(u1.w & 0xFFFF0000u), a7);
    }

    a0 += __shfl_xor(a0, 16, 64); a0 += __shfl_xor(a0, 32, 64);
    a1 += __shfl_xor(a1, 16, 64); a1 += __shfl_xor(a1, 32, 64);
    a2 += __shfl_xor(a2, 16, 64); a2 += __shfl_xor(a2, 32, 64);
    a3 += __shfl_xor(a3, 16, 64); a3 += __shfl_xor(a3, 32, 64);
    a4 += __shfl_xor(a4, 16, 64); a4 += __shfl_xor(a4, 32, 64);
    a5 += __shfl_xor(a5, 16, 64); a5 += __shfl_xor(a5, 32, 64);
    a6 += __shfl_xor(a6, 16, 64); a6 += __shfl_xor(a6, 32, 64);
    a7 += __shfl_xor(a7, 16, 64); a7 += __shfl_xor(a7, 32, 64);

    if (g == 0) {
        v4f* op = (v4f*)(out + ((size_t)row << 7) + t * 8);
        v4f o0; o0.x = a0; o0.y = a1; o0.z = a2; o0.w = a3;
        v4f o1; o1.x = a4; o1.y = a5; o1.z = a6; o1.w = a7;
        __builtin_nontemporal_store(o0, op);
        __builtin_nontemporal_store(o1, op + 1);
    }
}

// Cleanup: overflow edges (tens at most) — atomic add into out after gather.
__global__ void cleanup_kernel(const unsigned short* __restrict__ xt,
                               const int* __restrict__ ocount,
                               const int4* __restrict__ oedges,
                               float* __restrict__ out) {
    int tt = blockIdx.x * blockDim.x + threadIdx.x;
    int e = tt >> 5, sub = tt & 31;
    int n = *ocount;
    n = n < OCAP ? n : OCAP;
    if (e >= n) return;
    int4 q = oedges[e];
    float w = __int_as_float(q.z);
    const unsigned* xr = (const unsigned*)(xt + ((size_t)q.y << 7));
    unsigned u0 = xr[sub * 2], u1 = xr[sub * 2 + 1];
    float* o = out + ((size_t)q.x << 7) + sub * 4;
    atomicAdd(o + 0, w * __uint_as_float(u0 << 16));
    atomicAdd(o + 1, w * __uint_as_float(u0 & 0xFFFF0000u));
    atomicAdd(o + 2, w * __uint_as_float(u1 << 16));
    atomicAdd(o + 3, w * __uint_as_float(u1 & 0xFFFF0000u));
}

// ===================== fallback (tiny ws; never expected) ===================
__global__ void fallback_kernel(const float* __restrict__ x,
                                const int* __restrict__ rows,
                                const int* __restrict__ cols,
                                const float* __restrict__ vals,
                                float* __restrict__ out, int n_edges) {
    int gid = blockIdx.x * blockDim.x + threadIdx.x;
    int e = gid >> 5, t = gid & 31;
    if (e >= n_edges) return;
    int c = cols[e];
    const float* xr = x + (size_t)c * D_FEAT;
    float ss = 0.0f;
    for (int i = 0; i < D_FEAT; ++i) ss += xr[i] * xr[i];
    float nc = fmaxf(sqrtf(ss), 1e-15f);
    float u = fminf(nc, 1.0f - 1e-15f);
    float w = vals[e] * (0.5f * (log1pf(u) - log1pf(-u))) / nc;
    const float4* xc = (const float4*)xr;
    float4 xv = xc[t];
    float* o = out + (size_t)rows[e] * D_FEAT + t * 4;
    atomicAdd(o + 0, w * xv.x);
    atomicAdd(o + 1, w * xv.y);
    atomicAdd(o + 2, w * xv.z);
    atomicAdd(o + 3, w * xv.w);
}

// ============================================================================

extern "C" void kernel_launch(void* const* d_in, const int* in_sizes, int n_in,
                              void* d_out, int out_size, void* d_ws, size_t ws_size,
                              hipStream_t stream) {
    const float* x    = (const float*)d_in[0];
    const int*   rows = (const int*)d_in[1];
    const int*   cols = (const int*)d_in[2];
    const float* vals = (const float*)d_in[3];
    float* out = (float*)d_out;

    const int n_nodes = in_sizes[0] / D_FEAT;  // 50000
    const int n_edges = in_sizes[1];           // 800000

    char* wsb = (char*)d_ws;
    const int n_scatter_blocks = (n_edges + 2047) / 2048;  // 391
    const int n_scale_blocks   = (n_nodes + 3) / 4;        // 12500

    size_t xt_bytes    = (size_t)n_nodes * D_FEAT * 2;            // 12.8 MB
    size_t cnt_off     = xt_bytes;
    size_t ocount_off  = cnt_off + (size_t)n_nodes * 4;
    size_t oedges_off  = (ocount_off + 4 + 255) & ~(size_t)255;
    size_t buckets_off = (oedges_off + (size_t)OCAP * 16 + 511) & ~(size_t)511;
    size_t need        = buckets_off + (size_t)n_nodes * CAP * 8; // ~26 MB

    if (ws_size >= need) {
        unsigned short* xt = (unsigned short*)wsb;
        int*  cnt     = (int*)(wsb + cnt_off);
        int*  ocount  = (int*)(wsb + ocount_off);
        int4* oedges  = (int4*)(wsb + oedges_off);
        int*  buckets = (int*)(wsb + buckets_off);

        hipMemsetAsync(cnt, 0, ocount_off + 4 - cnt_off, stream);
        scatter_scale_kernel<<<n_scatter_blocks + n_scale_blocks, 256, 0, stream>>>(
            x, xt, rows, cols, vals, cnt, buckets, ocount, oedges,
            n_nodes, n_edges, n_scatter_blocks);
        gather_bucket_kernel<<<(n_nodes + 3) / 4, 256, 0, stream>>>(
            xt, cnt, buckets, out, n_nodes);
        cleanup_kernel<<<(OCAP * 32) / 256, 256, 0, stream>>>(xt, ocount, oedges, out);
    } else {
        hipMemsetAsync(out, 0, (size_t)out_size * sizeof(float), stream);
        long long total = (long long)n_edges * 32;
        fallback_kernel<<<(int)((total + 255) / 256), 256, 0, stream>>>(
            x, rows, cols, vals, out, n_edges);
    }
}